// Round 4
// baseline (253.316 us; speedup 1.0000x reference)
//
#include <hip/hip_runtime.h>

#define T_DIM 60
#define LOSS_BLOCKS 3840          // x 64 elems x 4 iters = 983040 = NT
#define PARTIALS_OFF 64           // ws floats: [0..59]=npred, [64..]=partials

__global__ void init_kernel(float* __restrict__ ws_npred) {
    int i = threadIdx.x;
    if (i < T_DIM) ws_npred[i] = 0.0f;
}

// n_pred[t] = sum_n mask[n,t]; coalesced grid-stride read, LDS bins.
// 60 distinct global addresses x 240 blocks -> pipelined chains, hidden.
__global__ void npred_kernel(const float* __restrict__ mask,
                             float* __restrict__ ws_npred, int NT) {
    __shared__ float bins[T_DIM];
    for (int j = threadIdx.x; j < T_DIM; j += blockDim.x) bins[j] = 0.0f;
    __syncthreads();
    int stride = gridDim.x * blockDim.x;
    for (int i = blockIdx.x * blockDim.x + threadIdx.x; i < NT; i += stride) {
        int t = i % T_DIM;
        atomicAdd(&bins[t], mask[i]);
    }
    __syncthreads();
    for (int j = threadIdx.x; j < T_DIM; j += blockDim.x)
        atomicAdd(&ws_npred[j], bins[j]);
}

// Quad-cooperative, coalesced: 4 lanes per (n,t) element; lane l owns mixture
// components {l, l+4}. Per wave-instruction the 64 lanes read CONSECUTIVE
// float4/float2 chunks (sigma: 16 full 128B lines/instr, mu: 8 lines/instr)
// vs round-1's divergent lane-stride-128B pattern (~64 line-requests/instr).
// 4-deep grid-stride keeps the block count at 3840 (epilogue cost == round 3).
// NO global atomic: plain per-block partial store (round-2's 204us was the
// 15360-deep same-address atomic convoy, ~30cy each, not its load pattern).
__global__ __launch_bounds__(256)
void loss_kernel(const float* __restrict__ mu,
                 const float* __restrict__ sigma,
                 const float* __restrict__ pi,
                 const float* __restrict__ x,
                 const float* __restrict__ mask,
                 const float* __restrict__ ws_npred,
                 float* __restrict__ ws_partials, int NT) {
    const float LOG_2PI = 1.8378770664093453f;
    int tid = threadIdx.x;
    int l = tid & 3;                       // lane within quad
    int quad = tid >> 2;                   // 0..63: element slot in this iter
    float acc = 0.0f;

#pragma unroll
    for (int iter = 0; iter < 4; ++iter) {
        int gid = (iter * LOSS_BLOCKS + blockIdx.x) * 64 + quad;
        if (gid < NT) {
            int n = gid / T_DIM;
            int t = gid - n * T_DIM;

            float2 xv = ((const float2*)x)[gid];
            float mk = mask[gid];
            float npr = ws_npred[t];

            // mu: element = 16 floats; lane grabs float2 #l and #(l+4)
            const float2* mu2 = (const float2*)(mu + (size_t)gid * 16);
            float2 m_lo = mu2[l];
            float2 m_hi = mu2[l + 4];
            // sigma: element = 8 float4 (one 128B line); lane grabs #l, #(l+4)
            const float4* sg4 = (const float4*)(sigma + (size_t)gid * 32);
            float4 s_lo = sg4[l];
            float4 s_hi = sg4[l + 4];
            // pi logits for this lane's two components (L1-resident)
            const float* pib = pi + (size_t)n * 8;
            float p_lo = pib[l];
            float p_hi = pib[l + 4];

            // closed-form 2x2: det = ac - b^2, maha = (c d1^2 - 2b d1d2 + a d2^2)/det
            float lp0, lp1;
            {
                float a = s_lo.x, b = s_lo.y, c = s_lo.w;
                float d1 = xv.x - m_lo.x, d2 = xv.y - m_lo.y;
                float det = a * c - b * b;
                float maha = (c * d1 * d1 - 2.0f * b * d1 * d2 + a * d2 * d2) / det;
                lp0 = p_lo - LOG_2PI - 0.5f * (maha + __logf(det));
            }
            {
                float a = s_hi.x, b = s_hi.y, c = s_hi.w;
                float d1 = xv.x - m_hi.x, d2 = xv.y - m_hi.y;
                float det = a * c - b * b;
                float maha = (c * d1 * d1 - 2.0f * b * d1 * d2 + a * d2 * d2) / det;
                lp1 = p_hi - LOG_2PI - 0.5f * (maha + __logf(det));
            }

            // LSE over 8 components across the quad (xor 1,2 stay in-quad)
            float mx = fmaxf(lp0, lp1);
            mx = fmaxf(mx, __shfl_xor(mx, 1));
            mx = fmaxf(mx, __shfl_xor(mx, 2));
            float s = __expf(lp0 - mx) + __expf(lp1 - mx);
            s += __shfl_xor(s, 1);
            s += __shfl_xor(s, 2);
            float lse_num = mx + __logf(s);

            // LSE over pi logits (normalizer)
            float pmx = fmaxf(p_lo, p_hi);
            pmx = fmaxf(pmx, __shfl_xor(pmx, 1));
            pmx = fmaxf(pmx, __shfl_xor(pmx, 2));
            float ps = __expf(p_lo - pmx) + __expf(p_hi - pmx);
            ps += __shfl_xor(ps, 1);
            ps += __shfl_xor(ps, 2);
            float lse_pi = pmx + __logf(ps);

            float v = (lse_pi - lse_num) * mk / npr;  // -gmm_lp, masked & scaled
            if (l == 0) acc += v;
        }
    }

    // wave (64) shuffle reduce -> LDS -> one plain store per block
#pragma unroll
    for (int off = 32; off > 0; off >>= 1)
        acc += __shfl_down(acc, off);
    __shared__ float wsum[4];
    int lane = tid & 63;
    int wid = tid >> 6;
    if (lane == 0) wsum[wid] = acc;
    __syncthreads();
    if (tid == 0)
        ws_partials[blockIdx.x] = wsum[0] + wsum[1] + wsum[2] + wsum[3];
}

// Single block sums the 3840 block partials into out[0].
__global__ void finalize_kernel(const float* __restrict__ ws_partials,
                                float* __restrict__ out, int nblocks) {
    float s = 0.0f;
    for (int i = threadIdx.x; i < nblocks; i += blockDim.x)
        s += ws_partials[i];
#pragma unroll
    for (int off = 32; off > 0; off >>= 1)
        s += __shfl_down(s, off);
    __shared__ float wsum[4];
    int lane = threadIdx.x & 63;
    int wid = threadIdx.x >> 6;
    if (lane == 0) wsum[wid] = s;
    __syncthreads();
    if (threadIdx.x == 0)
        out[0] = wsum[0] + wsum[1] + wsum[2] + wsum[3];
}

extern "C" void kernel_launch(void* const* d_in, const int* in_sizes, int n_in,
                              void* d_out, int out_size, void* d_ws, size_t ws_size,
                              hipStream_t stream) {
    const float* mu    = (const float*)d_in[0];   // (N,T,M,K)
    const float* sigma = (const float*)d_in[1];   // (N,T,M,K,K)
    const float* pi    = (const float*)d_in[2];   // (N,M)
    const float* x     = (const float*)d_in[3];   // (N,T,K)
    const float* mask  = (const float*)d_in[4];   // (N,T)
    float* out = (float*)d_out;
    float* ws_npred    = (float*)d_ws;                 // 60 floats
    float* ws_partials = (float*)d_ws + PARTIALS_OFF;  // 3840 floats

    int NT = in_sizes[4];                          // N*T = 983040

    hipLaunchKernelGGL(init_kernel, dim3(1), dim3(64), 0, stream, ws_npred);
    hipLaunchKernelGGL(npred_kernel, dim3(240), dim3(256), 0, stream,
                       mask, ws_npred, NT);
    hipLaunchKernelGGL(loss_kernel, dim3(LOSS_BLOCKS), dim3(256), 0, stream,
                       mu, sigma, pi, x, mask, ws_npred, ws_partials, NT);
    hipLaunchKernelGGL(finalize_kernel, dim3(1), dim3(256), 0, stream,
                       ws_partials, out, LOSS_BLOCKS);
}